// Round 2
// baseline (109.649 us; speedup 1.0000x reference)
//
#include <hip/hip_runtime.h>

#define BB 32
#define TT 12
#define NN 512
#define FF 64
#define HH 64
#define NBLK 32                   // n-values per block
#define NCHUNK (NN / NBLK)        // 16
#define GRID (BB * NCHUNK)        // 512 blocks

// ws float layout: [0..143]=S accum, [144..207]=wq rowsums, [208..271]=wk rowsums,
//                  [272]=sum(bq), [273]=sum(bk)
#define WS_S  0
#define WS_WQ 144
#define WS_WK 208
#define WS_BQ 272
#define WS_BK 273

// ---------------------------------------------------------------------------
// Init: zero the 12x12 accumulator and precompute weight row-sums + bias sums.
// Replaces the former hipMemsetAsync dispatch (same launch count).
// ---------------------------------------------------------------------------
__global__ __launch_bounds__(384) void fft_sel_init(
    const float* __restrict__ Wq, const float* __restrict__ bq,
    const float* __restrict__ Wk, const float* __restrict__ bk,
    float* __restrict__ ws)
{
    const int tid = threadIdx.x;
    if (tid < TT * TT) {
        ws[WS_S + tid] = 0.f;
    } else if (tid >= 144 && tid < 144 + FF) {
        const int f = tid - 144;
        float a = 0.f;
        #pragma unroll
        for (int h = 0; h < HH; ++h) a += Wq[f * HH + h];
        ws[WS_WQ + f] = a;
    } else if (tid >= 208 && tid < 208 + FF) {
        const int f = tid - 208;
        float a = 0.f;
        #pragma unroll
        for (int h = 0; h < HH; ++h) a += Wk[f * HH + h];
        ws[WS_WK + f] = a;
    } else if (tid == 272) {
        float a = 0.f;
        #pragma unroll
        for (int h = 0; h < HH; ++h) a += bq[h];
        ws[WS_BQ] = a;
    } else if (tid == 273) {
        float a = 0.f;
        #pragma unroll
        for (int h = 0; h < HH; ++h) a += bk[h];
        ws[WS_BK] = a;
    }
}

// ---------------------------------------------------------------------------
// Main: fully-coalesced fused linear + 12x12 cross-gram partial.
// 16 lanes cooperate per 64-float row -> each wave load instr = contiguous 1KB.
// ---------------------------------------------------------------------------
__global__ __launch_bounds__(256) void fft_sel_main(
    const float* __restrict__ x,   // [B,T,N,F]
    const float* __restrict__ ws,  // header (weights/biases) + S accum
    float* __restrict__ S)         // == ws + WS_S
{
    __shared__ float sq[TT][NBLK + 1];   // +1 pad: conflict-free outer product
    __shared__ float sk[TT][NBLK + 1];

    const int tid  = threadIdx.x;
    const int wave = tid >> 6;
    const int lane = tid & 63;
    const int sub  = lane >> 4;   // which of 4 rows this wave-quarter handles
    const int q    = lane & 15;   // which float4 of the row

    // Per-lane weight fragment (registers, broadcast L2 reads; loop-invariant).
    const float4 wqv = *(const float4*)(ws + WS_WQ + 4 * q);
    const float4 wkv = *(const float4*)(ws + WS_WK + 4 * q);
    const float  bqs = ws[WS_BQ];
    const float  bks = ws[WS_BK];

    const int b  = blockIdx.x >> 4;            // / NCHUNK
    const int n0 = (blockIdx.x & (NCHUNK - 1)) * NBLK;

    // 12*32 = 384 rows; 16 rows per block-iteration (4 waves x 4 rows).
    #pragma unroll
    for (int it = 0; it < (TT * NBLK) / 16; ++it) {   // 24 iterations
        const int r  = it * 16 + wave * 4 + sub;
        const int t  = r >> 5;        // / NBLK
        const int nl = r & (NBLK - 1);
        const float4 v = *(const float4*)(x +
            (((size_t)b * TT + t) * NN + (n0 + nl)) * FF + q * 4);
        float pq = v.x * wqv.x + v.y * wqv.y + v.z * wqv.z + v.w * wqv.w;
        float pk = v.x * wkv.x + v.y * wkv.y + v.z * wkv.z + v.w * wkv.w;
        #pragma unroll
        for (int off = 1; off < 16; off <<= 1) {
            pq += __shfl_xor(pq, off);
            pk += __shfl_xor(pk, off);
        }
        if (q == 0) {
            sq[t][nl] = pq + bqs;
            sk[t][nl] = pk + bks;
        }
    }
    __syncthreads();

    // 144 threads: (i,j) partial cross-gram over this block's 32 n's.
    if (tid < TT * TT) {
        const int i = tid / TT;
        const int j = tid % TT;
        float acc = 0.f;
        #pragma unroll
        for (int nl = 0; nl < NBLK; ++nl) acc += sq[i][nl] * sk[j][nl];
        atomicAdd(&S[tid], acc);
    }
}

// ---------------------------------------------------------------------------
// Final: scale + per-row stable top-4 (strict '>' == lax.top_k tie rule).
// Writes scores [12,4] then indices-as-float [12,4].
// ---------------------------------------------------------------------------
__global__ void fft_sel_final(const float* __restrict__ S, float* __restrict__ out)
{
    const int i = threadIdx.x;
    if (i >= TT) return;
    const float scale = 1.0f / ((float)BB * (float)NN * (float)HH);
    float v[TT];
    bool used[TT];
    #pragma unroll
    for (int j = 0; j < TT; ++j) { v[j] = S[i * TT + j] * scale; used[j] = false; }
    #pragma unroll
    for (int s = 0; s < 4; ++s) {
        float best = -INFINITY;
        int bi = 0;
        for (int j = 0; j < TT; ++j) {
            if (!used[j] && v[j] > best) { best = v[j]; bi = j; }
        }
        used[bi] = true;
        out[i * 4 + s]          = best;
        out[TT * 4 + i * 4 + s] = (float)bi;
    }
}

extern "C" void kernel_launch(void* const* d_in, const int* in_sizes, int n_in,
                              void* d_out, int out_size, void* d_ws, size_t ws_size,
                              hipStream_t stream) {
    const float* x  = (const float*)d_in[0];
    const float* Wq = (const float*)d_in[1];
    const float* bq = (const float*)d_in[2];
    const float* Wk = (const float*)d_in[3];
    const float* bk = (const float*)d_in[4];
    float* ws = (float*)d_ws;

    fft_sel_init<<<1, 384, 0, stream>>>(Wq, bq, Wk, bk, ws);
    fft_sel_main<<<GRID, 256, 0, stream>>>(x, ws, ws + WS_S);
    fft_sel_final<<<1, 64, 0, stream>>>(ws + WS_S, (float*)d_out);
}

// Round 3
// 97.720 us; speedup vs baseline: 1.1221x; 1.1221x over previous
//
#include <hip/hip_runtime.h>

#define BB 32
#define TT 12
#define NN 512
#define FF 64
#define HH 64
#define NBLK 8                    // n-values per block
#define NCHUNK (NN / NBLK)        // 64
#define GRID (BB * NCHUNK)        // 2048 blocks -> 8 blocks/CU
#define NSHADOW 16                // shadow copies of the 12x12 accumulator

// ws float layout:
//   [0 .. 16*144)            shadow S accumulators
//   [2304 .. 2368)           wq row-sums
//   [2368 .. 2432)           wk row-sums
//   [2432], [2433]           sum(bq), sum(bk)
#define WS_SH 0
#define WS_WQ (NSHADOW * TT * TT)       // 2304
#define WS_WK (WS_WQ + FF)              // 2368
#define WS_BQ (WS_WK + FF)              // 2432
#define WS_BK (WS_BQ + 1)               // 2433

// ---------------------------------------------------------------------------
// Init: zero 16 shadow accumulators (2304 floats = 576 float4) and precompute
// weight row-sums + bias sums.
// ---------------------------------------------------------------------------
__global__ __launch_bounds__(1024) void fft_sel_init(
    const float* __restrict__ Wq, const float* __restrict__ bq,
    const float* __restrict__ Wk, const float* __restrict__ bk,
    float* __restrict__ ws)
{
    const int tid = threadIdx.x;
    if (tid < 576) {
        ((float4*)ws)[tid] = make_float4(0.f, 0.f, 0.f, 0.f);
    } else if (tid < 576 + FF) {
        const int f = tid - 576;
        float a = 0.f;
        #pragma unroll
        for (int h = 0; h < HH; ++h) a += Wq[f * HH + h];
        ws[WS_WQ + f] = a;
    } else if (tid < 576 + 2 * FF) {
        const int f = tid - (576 + FF);
        float a = 0.f;
        #pragma unroll
        for (int h = 0; h < HH; ++h) a += Wk[f * HH + h];
        ws[WS_WK + f] = a;
    } else if (tid == 576 + 2 * FF) {
        float a = 0.f;
        #pragma unroll
        for (int h = 0; h < HH; ++h) a += bq[h];
        ws[WS_BQ] = a;
    } else if (tid == 576 + 2 * FF + 1) {
        float a = 0.f;
        #pragma unroll
        for (int h = 0; h < HH; ++h) a += bk[h];
        ws[WS_BK] = a;
    }
}

// ---------------------------------------------------------------------------
// Main: fused linear + 12x12 cross-gram partial, full occupancy.
// 16 lanes per 64-float row; every wave load instruction covers contiguous
// memory. 2048 blocks * 4 waves = 32 waves/CU.
// ---------------------------------------------------------------------------
__global__ __launch_bounds__(256, 8) void fft_sel_main(
    const float* __restrict__ x,   // [B,T,N,F]
    const float* __restrict__ ws)
{
    __shared__ float sq[TT][NBLK];
    __shared__ float sk[TT][NBLK];

    const int tid = threadIdx.x;
    const int q   = tid & 15;     // which float4 of the row

    // Loop-invariant per-lane weight fragment (L2-broadcast reads).
    const float4 wqv = *(const float4*)(ws + WS_WQ + 4 * q);
    const float4 wkv = *(const float4*)(ws + WS_WK + 4 * q);
    const float  bqs = ws[WS_BQ];
    const float  bks = ws[WS_BK];

    const int b  = blockIdx.x >> 6;               // / NCHUNK
    const int n0 = (blockIdx.x & (NCHUNK - 1)) * NBLK;

    // 12*8 = 96 rows * 16 lane-slots = 1536 slots; 256 threads -> 6 iters.
    #pragma unroll
    for (int it = 0; it < (TT * NBLK * 16) / 256; ++it) {   // 6
        const int s   = it * 256 + tid;
        const int row = s >> 4;              // 0..95
        const int t   = row >> 3;            // / NBLK
        const int nl  = row & (NBLK - 1);
        const float4 v = *(const float4*)(x +
            (((size_t)b * TT + t) * NN + (n0 + nl)) * FF + q * 4);
        float pq = v.x * wqv.x + v.y * wqv.y + v.z * wqv.z + v.w * wqv.w;
        float pk = v.x * wkv.x + v.y * wkv.y + v.z * wkv.z + v.w * wkv.w;
        #pragma unroll
        for (int off = 1; off < 16; off <<= 1) {
            pq += __shfl_xor(pq, off);
            pk += __shfl_xor(pk, off);
        }
        if (q == 0) {
            sq[t][nl] = pq + bqs;
            sk[t][nl] = pk + bks;
        }
    }
    __syncthreads();

    // 144 threads: (i,j) partial cross-gram over this block's 8 n's.
    // Scatter across 16 shadow accumulators to cap same-address contention
    // at 2048/16 = 128 serialized atomics per address.
    if (tid < TT * TT) {
        const int i = tid / TT;
        const int j = tid % TT;
        float acc = 0.f;
        #pragma unroll
        for (int nl = 0; nl < NBLK; ++nl) acc += sq[i][nl] * sk[j][nl];
        float* S = (float*)ws + WS_SH + (blockIdx.x & (NSHADOW - 1)) * (TT * TT);
        atomicAdd(&S[tid], acc);
    }
}

// ---------------------------------------------------------------------------
// Final: fold shadows, scale, per-row stable top-4 (strict '>' == lax.top_k
// tie rule). Writes scores [12,4] then indices-as-float [12,4].
// ---------------------------------------------------------------------------
__global__ __launch_bounds__(256) void fft_sel_final(
    const float* __restrict__ ws, float* __restrict__ out)
{
    __shared__ float S[TT * TT];
    const int tid = threadIdx.x;
    if (tid < TT * TT) {
        const float scale = 1.0f / ((float)BB * (float)NN * (float)HH);
        float a = 0.f;
        #pragma unroll
        for (int c = 0; c < NSHADOW; ++c) a += ws[WS_SH + c * TT * TT + tid];
        S[tid] = a * scale;
    }
    __syncthreads();
    if (tid < TT) {
        const int i = tid;
        float v[TT];
        bool used[TT];
        #pragma unroll
        for (int j = 0; j < TT; ++j) { v[j] = S[i * TT + j]; used[j] = false; }
        #pragma unroll
        for (int s = 0; s < 4; ++s) {
            float best = -INFINITY;
            int bi = 0;
            for (int j = 0; j < TT; ++j) {
                if (!used[j] && v[j] > best) { best = v[j]; bi = j; }
            }
            used[bi] = true;
            out[i * 4 + s]          = best;
            out[TT * 4 + i * 4 + s] = (float)bi;
        }
    }
}

extern "C" void kernel_launch(void* const* d_in, const int* in_sizes, int n_in,
                              void* d_out, int out_size, void* d_ws, size_t ws_size,
                              hipStream_t stream) {
    const float* x  = (const float*)d_in[0];
    const float* Wq = (const float*)d_in[1];
    const float* bq = (const float*)d_in[2];
    const float* Wk = (const float*)d_in[3];
    const float* bk = (const float*)d_in[4];
    float* ws = (float*)d_ws;

    fft_sel_init<<<1, 1024, 0, stream>>>(Wq, bq, Wk, bk, ws);
    fft_sel_main<<<GRID, 256, 0, stream>>>(x, ws);
    fft_sel_final<<<1, 256, 0, stream>>>(ws, (float*)d_out);
}